// Round 3
// baseline (86.814 us; speedup 1.0000x reference)
//
#include <hip/hip_runtime.h>
#include <hip/hip_bf16.h>

#define BB 128      // batch
#define SS 128      // seq len
#define VD 128      // VALUE_DIM
#define CN 64       // CONCEPT_NUM
#define KD 128      // KEY_DIM
#define QN 10000
#define MROWS (2*BB*SS)       // 32768
#define MTOT  (MROWS + BB)    // 32896

typedef __attribute__((ext_vector_type(8))) short bf16x8;
typedef __attribute__((ext_vector_type(4))) float f32x4;
typedef __attribute__((ext_vector_type(2))) float f32x2;

__device__ __forceinline__ float bflo(unsigned int u) { return __uint_as_float(u << 16); }
__device__ __forceinline__ float bfhi(unsigned int u) { return __uint_as_float(u & 0xffff0000u); }
__device__ __forceinline__ unsigned short f2bf(float f) {
    unsigned int x = __float_as_uint(f);
    return (unsigned short)((x + 0x7fffu + ((x >> 16) & 1u)) >> 16);
}
__device__ __forceinline__ unsigned int pk2(float lo, float hi) {
    return (unsigned int)f2bf(lo) | ((unsigned int)f2bf(hi) << 16);
}
__device__ __forceinline__ float fast_tanh(float x) {
    float e = __expf(2.0f * x);
    return 1.0f - 2.0f / (e + 1.0f);
}
__device__ __forceinline__ float fast_sig(float x) {
    return 1.0f / (1.0f + __expf(-x));
}

// ---------------- kernel 1: weight pack (blocks 0..19) + counts (block 20) ----------------
// Bfrag[(g*4+kt)*64 + lane] = 8 bf16: W[n][k], n = g*16 + (lane&15), k = kt*32 + (lane>>4)*8 + i
__global__ __launch_bounds__(256) void k_wcnt(
    const float* __restrict__ erase_W, const float* __restrict__ add_W,
    const float* __restrict__ key_W, unsigned short* __restrict__ Bfrag,
    const int* __restrict__ ri, const int* __restrict__ wi, float* __restrict__ sig)
{
    if (blockIdx.x < 20) {
        const int bid = blockIdx.x * 4 + (threadIdx.x >> 6);   // 0..79
        const int l = threadIdx.x & 63;
        const int n = (bid >> 2) * 16 + (l & 15);
        const int k0 = (bid & 3) * 32 + (l >> 4) * 8;
        const float* src;
        if (n < 128)      src = erase_W + (size_t)n * KD + k0;
        else if (n < 256) src = add_W + (size_t)(n - 128) * KD + k0;
        else              src = key_W + (size_t)(n - 256) * KD + k0;
        float4 fa = ((const float4*)src)[0];
        float4 fb = ((const float4*)src)[1];
        uint4 o = make_uint4(pk2(fa.x, fa.y), pk2(fa.z, fa.w), pk2(fb.x, fb.y), pk2(fb.z, fb.w));
        *(uint4*)(Bfrag + ((size_t)bid * 64 + l) * 8) = o;
    } else {
        __shared__ int sr_s[4], sw_s[4];
        const int t = threadIdx.x;
        const int4* r4 = (const int4*)ri;
        const int4* w4 = (const int4*)wi;
        int sr = 0, sw = 0;
        #pragma unroll 4
        for (int p = 0; p < 16; ++p) {
            int4 a = r4[p * 256 + t];
            int4 b = w4[p * 256 + t];
            sr += (a.x >= 1) + (a.y >= 1) + (a.z >= 1) + (a.w >= 1);
            sw += (b.x >= 1) + (b.y >= 1) + (b.z >= 1) + (b.w >= 1);
        }
        for (int off = 1; off < 64; off <<= 1) { sr += __shfl_xor(sr, off); sw += __shfl_xor(sw, off); }
        int wid = t >> 6;
        if ((t & 63) == 0) { sr_s[wid] = sr; sw_s[wid] = sw; }
        __syncthreads();
        if (t == 0) {
            int SR = sr_s[0]+sr_s[1]+sr_s[2]+sr_s[3];
            int SW = sw_s[0]+sw_s[1]+sw_s[2]+sw_s[3];
            sig[0] = 1.0f / (1.0f + __expf(-(float)SR));
            sig[1] = 1.0f / (1.0f + __expf(-(float)SW));
        }
    }
}

// ---------------- kernel 2: MFMA precompute -> ET/AT (bf16, [chain][v][s]) + Wf (f32) / WT (f32) ----------------
__global__ __launch_bounds__(256) void k_mfma(
    const int* __restrict__ ri, const int* __restrict__ wi, const int* __restrict__ tgt,
    const float* __restrict__ q_emb, const float* __restrict__ i_emb,
    const float* __restrict__ erase_b, const float* __restrict__ add_b,
    const unsigned short* __restrict__ Bfrag,
    unsigned short* __restrict__ ETbuf, unsigned short* __restrict__ ATbuf,
    float* __restrict__ Wf, float* __restrict__ WTbuf)
{
    __shared__ __align__(16) char shA[32 * 256];      // Xi bf16, swizzled
    __shared__ __align__(16) char shB[32 * 68 * 4];   // Xq bf16 swizzled, then logits f32 [32][68]
    __shared__ int id_s[32], ir_s[32];

    const int t = threadIdx.x;
    const int lane = t & 63;
    const int w = t >> 6;
    const int base = blockIdx.x * 32;
    const bool ea = (base < MROWS);

    if (t < 32) {
        int r = base + t;
        int irow = 0, qid;
        if (r < MROWS) {
            int m = r >> 14;
            int idx = r & 16383;
            int inter = (m == 0) ? ri[idx] : wi[idx];
            irow = inter;
            qid = (inter > QN) ? inter - QN : inter;
        } else {
            qid = tgt[r - MROWS];
        }
        id_s[t] = qid; ir_s[t] = irow;
    }
    __syncthreads();

    // stage Xq (always) and Xi (if E/A block), bf16 + XOR-swizzle (byte ^= (row&7)<<4)
    {
        const int r = t >> 3, o = t & 7;
        const int bb = r * 256 + o * 32;
        const int sw = (r & 7) << 4;
        {
            const float* src = q_emb + (size_t)id_s[r] * KD + o * 16;
            float4 f0 = ((const float4*)src)[0];
            float4 f1 = ((const float4*)src)[1];
            float4 f2 = ((const float4*)src)[2];
            float4 f3 = ((const float4*)src)[3];
            *(uint4*)(shB + (bb ^ sw))        = make_uint4(pk2(f0.x,f0.y), pk2(f0.z,f0.w), pk2(f1.x,f1.y), pk2(f1.z,f1.w));
            *(uint4*)(shB + ((bb + 16) ^ sw)) = make_uint4(pk2(f2.x,f2.y), pk2(f2.z,f2.w), pk2(f3.x,f3.y), pk2(f3.z,f3.w));
        }
        if (ea) {
            const float* src = i_emb + (size_t)ir_s[r] * KD + o * 16;
            float4 f0 = ((const float4*)src)[0];
            float4 f1 = ((const float4*)src)[1];
            float4 f2 = ((const float4*)src)[2];
            float4 f3 = ((const float4*)src)[3];
            *(uint4*)(shA + (bb ^ sw))        = make_uint4(pk2(f0.x,f0.y), pk2(f0.z,f0.w), pk2(f1.x,f1.y), pk2(f1.z,f1.w));
            *(uint4*)(shA + ((bb + 16) ^ sw)) = make_uint4(pk2(f2.x,f2.y), pk2(f2.z,f2.w), pk2(f3.x,f3.y), pk2(f3.z,f3.w));
        }
    }
    __syncthreads();

    // ---- key logits GEMM: Xq(32x128) x key_W^T(128x64), wave w owns cols w*16..w*16+15 ----
    const int rowl = lane & 15;
    const int kb16 = (lane >> 4) * 16;

    bf16x8 afQ[2][4];
    #pragma unroll
    for (int mt = 0; mt < 2; ++mt)
        #pragma unroll
        for (int kt = 0; kt < 4; ++kt) {
            int row = mt * 16 + rowl;
            int addr = (row * 256 + kt * 64 + kb16) ^ ((row & 7) << 4);
            afQ[mt][kt] = *(const bf16x8*)(shB + addr);
        }

    f32x4 accK0 = {0.f,0.f,0.f,0.f}, accK1 = {0.f,0.f,0.f,0.f};
    {
        const int gk = 16 + w;
        #pragma unroll
        for (int kt = 0; kt < 4; ++kt) {
            bf16x8 bf = *(const bf16x8*)(Bfrag + ((size_t)(gk * 4 + kt) * 64 + lane) * 8);
            accK0 = __builtin_amdgcn_mfma_f32_16x16x32_bf16(afQ[0][kt], bf, accK0, 0, 0, 0);
            accK1 = __builtin_amdgcn_mfma_f32_16x16x32_bf16(afQ[1][kt], bf, accK1, 0, 0, 0);
        }
    }
    __syncthreads();   // done reading shB (Xq)

    // write logits to shB as f32 [32][68]
    {
        float* L = (float*)shB;
        const int col = w * 16 + rowl;
        const int rb4 = (lane >> 4) * 4;
        #pragma unroll
        for (int rr = 0; rr < 4; ++rr) L[(rb4 + rr) * 68 + col] = accK0[rr];
        #pragma unroll
        for (int rr = 0; rr < 4; ++rr) L[(16 + rb4 + rr) * 68 + col] = accK1[rr];
    }
    __syncthreads();

    // softmax over 64 cols: 8 threads per row, shfl-reduce in 8-lane groups
    {
        const float* L = (const float*)shB;
        const int rr = t >> 3, q = t & 7;
        float4 va = *(const float4*)(L + rr * 68 + q * 8);
        float4 vb = *(const float4*)(L + rr * 68 + q * 8 + 4);
        float mx = fmaxf(fmaxf(fmaxf(va.x, va.y), fmaxf(va.z, va.w)),
                         fmaxf(fmaxf(vb.x, vb.y), fmaxf(vb.z, vb.w)));
        #pragma unroll
        for (int off = 1; off < 8; off <<= 1) mx = fmaxf(mx, __shfl_xor(mx, off));
        float e0 = __expf(va.x - mx), e1 = __expf(va.y - mx), e2 = __expf(va.z - mx), e3 = __expf(va.w - mx);
        float e4 = __expf(vb.x - mx), e5 = __expf(vb.y - mx), e6 = __expf(vb.z - mx), e7 = __expf(vb.w - mx);
        float s = e0 + e1 + e2 + e3 + e4 + e5 + e6 + e7;
        #pragma unroll
        for (int off = 1; off < 8; off <<= 1) s += __shfl_xor(s, off);
        float inv = 1.0f / s;
        int R = base + rr;
        if (R < MROWS) {
            float* dw = Wf + (size_t)R * CN + q * 8;
            *(float4*)dw       = make_float4(e0*inv, e1*inv, e2*inv, e3*inv);
            *(float4*)(dw + 4) = make_float4(e4*inv, e5*inv, e6*inv, e7*inv);
        } else {
            float* dst = WTbuf + (size_t)(R - MROWS) * CN + q * 8;
            *(float4*)dst       = make_float4(e0*inv, e1*inv, e2*inv, e3*inv);
            *(float4*)(dst + 4) = make_float4(e4*inv, e5*inv, e6*inv, e7*inv);
        }
    }

    // ---- E/A GEMM: Xi(32x128) x [erase;add]^T(128x256); wave w owns g = w, w+4, w+8, w+12 ----
    // Epilogue writes TRANSPOSED: ET/AT[(chain*VD + cc)*SS + s], s = row index within chain.
    if (ea) {
        bf16x8 afI[2][4];
        #pragma unroll
        for (int mt = 0; mt < 2; ++mt)
            #pragma unroll
            for (int kt = 0; kt < 4; ++kt) {
                int row = mt * 16 + rowl;
                int addr = (row * 256 + kt * 64 + kb16) ^ ((row & 7) << 4);
                afI[mt][kt] = *(const bf16x8*)(shA + addr);
            }

        const int rb4 = (lane >> 4) * 4;
        const int chain = base >> 7;          // block's 32 rows lie in one chain
        const int sbase = base & 127;
        #pragma unroll
        for (int gi = 0; gi < 4; ++gi) {
            const int g = w + gi * 4;            // 0..15
            f32x4 a0 = {0.f,0.f,0.f,0.f}, a1 = {0.f,0.f,0.f,0.f};
            #pragma unroll
            for (int kt = 0; kt < 4; ++kt) {
                bf16x8 bf = *(const bf16x8*)(Bfrag + ((size_t)(g * 4 + kt) * 64 + lane) * 8);
                a0 = __builtin_amdgcn_mfma_f32_16x16x32_bf16(afI[0][kt], bf, a0, 0, 0, 0);
                a1 = __builtin_amdgcn_mfma_f32_16x16x32_bf16(afI[1][kt], bf, a1, 0, 0, 0);
            }
            const bool isE = (g < 8);
            const int cc = (g & 7) * 16 + rowl;  // col within E or A (0..127) == v
            const float bv = isE ? erase_b[cc] : add_b[cc];
            unsigned short* dst = (isE ? ETbuf : ATbuf) + ((size_t)chain * VD + cc) * SS;
            #pragma unroll
            for (int mt = 0; mt < 2; ++mt) {
                f32x4 av = mt ? a1 : a0;
                const int s0 = sbase + mt * 16 + rb4;   // rr increments s by 1
                ushort4 o;
                float x0 = av[0] + bv, x1 = av[1] + bv, x2 = av[2] + bv, x3 = av[3] + bv;
                if (isE) {
                    o.x = f2bf(fast_sig(x0)); o.y = f2bf(fast_sig(x1));
                    o.z = f2bf(fast_sig(x2)); o.w = f2bf(fast_sig(x3));
                } else {
                    o.x = f2bf(fast_tanh(x0)); o.y = f2bf(fast_tanh(x1));
                    o.z = f2bf(fast_tanh(x2)); o.w = f2bf(fast_tanh(x3));
                }
                *(ushort4*)(dst + s0) = o;
            }
        }
    }
}

// ---------------- kernel 3: the scan (linear recurrence) + final read ----------------
__global__ __launch_bounds__(1024) void k_scan(
    const unsigned short* __restrict__ ETbuf, const unsigned short* __restrict__ ATbuf,
    const float* __restrict__ Wf, const float* __restrict__ WTbuf,
    const float* __restrict__ rmem0, const float* __restrict__ wmem0,
    float* __restrict__ readbuf)
{
    __shared__ float psum[8 * 128];
    const int t  = threadIdx.x;
    const int chain = blockIdx.x;       // m*BB + b
    const int m  = chain >> 7;
    const int b  = chain & 127;
    const int ck = t >> 7;              // 0..7  (wave-uniform)
    const int v  = t & 127;
    const int c0 = ck * 8;

    const float* minit = (m == 0) ? rmem0 : wmem0;
    f32x2 mm[4];
    #pragma unroll
    for (int j = 0; j < 4; ++j) {
        mm[j].x = minit[v * CN + c0 + 2*j];
        mm[j].y = minit[v * CN + c0 + 2*j + 1];
    }

    const unsigned short* Ep = ETbuf + ((size_t)chain * VD + v) * SS;
    const unsigned short* Ap = ATbuf + ((size_t)chain * VD + v) * SS;
    const float* Wp = Wf + (size_t)chain * SS * CN + c0;

    for (int sb = 0; sb < 16; ++sb) {
        uint4 eu = *(const uint4*)(Ep + sb * 8);
        uint4 au = *(const uint4*)(Ap + sb * 8);
        const float* wp = Wp + (size_t)sb * 8 * CN;
        #pragma unroll
        for (int c4 = 0; c4 < 4; ++c4) {
            unsigned int ew = ((const unsigned int*)&eu)[c4];
            unsigned int aw = ((const unsigned int*)&au)[c4];
            {
                float e = bflo(ew), a = bflo(aw);
                float4 w0 = *(const float4*)(wp + (size_t)(c4 * 2) * CN);
                float4 w1 = *(const float4*)(wp + (size_t)(c4 * 2) * CN + 4);
                f32x2 ev = {e, e}, av = {a, a}, g;
                f32x2 wv;
                g = av - ev * mm[0]; wv.x = w0.x; wv.y = w0.y; mm[0] += wv * g;
                g = av - ev * mm[1]; wv.x = w0.z; wv.y = w0.w; mm[1] += wv * g;
                g = av - ev * mm[2]; wv.x = w1.x; wv.y = w1.y; mm[2] += wv * g;
                g = av - ev * mm[3]; wv.x = w1.z; wv.y = w1.w; mm[3] += wv * g;
            }
            {
                float e = bfhi(ew), a = bfhi(aw);
                float4 w0 = *(const float4*)(wp + (size_t)(c4 * 2 + 1) * CN);
                float4 w1 = *(const float4*)(wp + (size_t)(c4 * 2 + 1) * CN + 4);
                f32x2 ev = {e, e}, av = {a, a}, g;
                f32x2 wv;
                g = av - ev * mm[0]; wv.x = w0.x; wv.y = w0.y; mm[0] += wv * g;
                g = av - ev * mm[1]; wv.x = w0.z; wv.y = w0.w; mm[1] += wv * g;
                g = av - ev * mm[2]; wv.x = w1.x; wv.y = w1.y; mm[2] += wv * g;
                g = av - ev * mm[3]; wv.x = w1.z; wv.y = w1.w; mm[3] += wv * g;
            }
        }
    }

    const float* wt = WTbuf + (size_t)b * CN + c0;
    float4 wa = *(const float4*)wt;
    float4 wb = *(const float4*)(wt + 4);
    float p = 0.0f;
    p = fmaf(mm[0].x, wa.x, p); p = fmaf(mm[0].y, wa.y, p);
    p = fmaf(mm[1].x, wa.z, p); p = fmaf(mm[1].y, wa.w, p);
    p = fmaf(mm[2].x, wb.x, p); p = fmaf(mm[2].y, wb.y, p);
    p = fmaf(mm[3].x, wb.z, p); p = fmaf(mm[3].y, wb.w, p);
    psum[ck * 128 + v] = p;
    __syncthreads();
    if (t < 128) {
        float s = 0.0f;
        #pragma unroll
        for (int j = 0; j < 8; ++j) s += psum[j * 128 + t];
        readbuf[(size_t)chain * VD + t] = s;
    }
}

// ---------------- kernel 4: head (256 threads, k-split) ----------------
__global__ __launch_bounds__(256) void k_head(
    const float* __restrict__ readbuf, const int* __restrict__ tgt,
    const float* __restrict__ q_emb,
    const float* __restrict__ rsum_W, const float* __restrict__ rsum_b,
    const float* __restrict__ wsum_W, const float* __restrict__ wsum_b,
    const float* __restrict__ succ_W, const float* __restrict__ succ_b,
    const float* __restrict__ fail_W, const float* __restrict__ fail_b,
    const float* __restrict__ diff_W, const float* __restrict__ diff_b,
    const float* __restrict__ sig, float* __restrict__ out)
{
    __shared__ float xr[256], xw[256];
    __shared__ float part[2][128];
    __shared__ float red_s[6];
    const int t = threadIdx.x;
    const int j = t & 127;
    const int h = t >> 7;
    const int b = blockIdx.x;
    if (h == 0) {
        int tid_ = tgt[b];
        float qv = q_emb[(size_t)tid_ * KD + j];
        xr[j]       = readbuf[(size_t)b * VD + j];
        xr[128 + j] = qv;
        xw[j]       = readbuf[(size_t)(BB + b) * VD + j];
        xw[128 + j] = qv;
    }
    __syncthreads();

    float rs = (h == 0) ? rsum_b[j] : 0.0f;
    float wv = (h == 0) ? wsum_b[j] : 0.0f;
    const float* rw = rsum_W + (size_t)j * 256 + h * 128;
    const float* ww = wsum_W + (size_t)j * 256 + h * 128;
    const float* xrp = xr + h * 128;
    const float* xwp = xw + h * 128;
    #pragma unroll 4
    for (int k = 0; k < 128; ++k) {
        rs = fmaf(rw[k], xrp[k], rs);
        wv = fmaf(ww[k], xwp[k], wv);
    }
    if (h == 1) { part[0][j] = rs; part[1][j] = wv; }
    __syncthreads();
    if (h == 0) {
        rs += part[0][j];
        wv += part[1][j];
        float r_sum = fast_tanh(rs), w_sum = fast_tanh(wv);
        float qv = xr[128 + j];
        float ps = r_sum * succ_W[j];
        float pf = w_sum * fail_W[j];
        float pd = qv    * diff_W[j];
        for (int off = 1; off < 64; off <<= 1) {
            ps += __shfl_xor(ps, off);
            pf += __shfl_xor(pf, off);
            pd += __shfl_xor(pd, off);
        }
        int wid = j >> 6;
        if ((j & 63) == 0) { red_s[wid*3+0] = ps; red_s[wid*3+1] = pf; red_s[wid*3+2] = pd; }
    }
    __syncthreads();
    if (t == 0) {
        float Ps = red_s[0] + red_s[3];
        float Pf = red_s[1] + red_s[4];
        float Pd = red_s[2] + red_s[5];
        float succ = fast_tanh(Ps + succ_b[0]);
        float fail = fast_tanh(Pf + fail_b[0]);
        float diff = fast_tanh(Pd + diff_b[0]);
        out[b] = succ * sig[0] + fail * sig[1] - 2.0f * diff;
    }
}

extern "C" void kernel_launch(void* const* d_in, const int* in_sizes, int n_in,
                              void* d_out, int out_size, void* d_ws, size_t ws_size,
                              hipStream_t stream) {
    const int*   ri      = (const int*)d_in[0];
    const int*   wi      = (const int*)d_in[1];
    const int*   tgt     = (const int*)d_in[2];
    const float* q_emb   = (const float*)d_in[3];
    const float* i_emb   = (const float*)d_in[4];
    const float* key_W   = (const float*)d_in[5];
    const float* erase_W = (const float*)d_in[6];
    const float* erase_b = (const float*)d_in[7];
    const float* add_W   = (const float*)d_in[8];
    const float* add_b   = (const float*)d_in[9];
    const float* rsum_W  = (const float*)d_in[10];
    const float* rsum_b  = (const float*)d_in[11];
    const float* wsum_W  = (const float*)d_in[12];
    const float* wsum_b  = (const float*)d_in[13];
    const float* succ_W  = (const float*)d_in[14];
    const float* succ_b  = (const float*)d_in[15];
    const float* fail_W  = (const float*)d_in[16];
    const float* fail_b  = (const float*)d_in[17];
    const float* diff_W  = (const float*)d_in[18];
    const float* diff_b  = (const float*)d_in[19];
    const float* rmem0   = (const float*)d_in[20];
    const float* wmem0   = (const float*)d_in[21];

    char* ws = (char*)d_ws;
    unsigned short* ETbuf   = (unsigned short*)(ws + 0);          //  8,388,608 B
    unsigned short* ATbuf   = (unsigned short*)(ws + 8388608);    //  8,388,608 B
    float*          Wf      = (float*)(ws + 16777216);            //  8,388,608 B
    float*          WTbuf   = (float*)(ws + 25165824);            //     32,768 B
    float*          readbuf = (float*)(ws + 25198592);            //    131,072 B
    unsigned short* Bfrag   = (unsigned short*)(ws + 25329664);   //     81,920 B
    float*          sig     = (float*)(ws + 25411584);            //          8 B
    float*          out     = (float*)d_out;

    hipLaunchKernelGGL(k_wcnt, dim3(21), dim3(256), 0, stream,
        erase_W, add_W, key_W, Bfrag, ri, wi, sig);
    hipLaunchKernelGGL(k_mfma, dim3(1028), dim3(256), 0, stream,
        ri, wi, tgt, q_emb, i_emb, erase_b, add_b, Bfrag,
        ETbuf, ATbuf, Wf, WTbuf);
    hipLaunchKernelGGL(k_scan, dim3(256), dim3(1024), 0, stream,
        ETbuf, ATbuf, Wf, WTbuf, rmem0, wmem0, readbuf);
    hipLaunchKernelGGL(k_head, dim3(128), dim3(256), 0, stream,
        readbuf, tgt, q_emb, rsum_W, rsum_b, wsum_W, wsum_b,
        succ_W, succ_b, fail_W, fail_b, diff_W, diff_b, sig, out);
}

// Round 4
// 77.064 us; speedup vs baseline: 1.1265x; 1.1265x over previous
//
#include <hip/hip_runtime.h>
#include <hip/hip_bf16.h>

#define BB 128      // batch
#define SS 128      // seq len
#define VD 128      // VALUE_DIM
#define CN 64       // CONCEPT_NUM
#define KD 128      // KEY_DIM
#define QN 10000
#define MROWS (2*BB*SS)       // 32768
#define MTOT  (MROWS + BB)    // 32896

typedef __attribute__((ext_vector_type(8))) short bf16x8;
typedef __attribute__((ext_vector_type(4))) float f32x4;
typedef __attribute__((ext_vector_type(2))) float f32x2;

__device__ __forceinline__ float bflo(unsigned int u) { return __uint_as_float(u << 16); }
__device__ __forceinline__ unsigned short f2bf(float f) {
    unsigned int x = __float_as_uint(f);
    return (unsigned short)((x + 0x7fffu + ((x >> 16) & 1u)) >> 16);
}
__device__ __forceinline__ unsigned int pk2(float lo, float hi) {
    return (unsigned int)f2bf(lo) | ((unsigned int)f2bf(hi) << 16);
}
__device__ __forceinline__ float fast_tanh(float x) {
    float e = __expf(2.0f * x);
    return 1.0f - 2.0f / (e + 1.0f);
}
__device__ __forceinline__ float fast_sig(float x) {
    return 1.0f / (1.0f + __expf(-x));
}

// ---------------- kernel 1: weight pack (blocks 0..19) + counts (block 20) ----------------
__global__ __launch_bounds__(256) void k_wcnt(
    const float* __restrict__ erase_W, const float* __restrict__ add_W,
    const float* __restrict__ key_W, unsigned short* __restrict__ Bfrag,
    const int* __restrict__ ri, const int* __restrict__ wi, float* __restrict__ sig)
{
    if (blockIdx.x < 20) {
        const int bid = blockIdx.x * 4 + (threadIdx.x >> 6);   // 0..79
        const int l = threadIdx.x & 63;
        const int n = (bid >> 2) * 16 + (l & 15);
        const int k0 = (bid & 3) * 32 + (l >> 4) * 8;
        const float* src;
        if (n < 128)      src = erase_W + (size_t)n * KD + k0;
        else if (n < 256) src = add_W + (size_t)(n - 128) * KD + k0;
        else              src = key_W + (size_t)(n - 256) * KD + k0;
        float4 fa = ((const float4*)src)[0];
        float4 fb = ((const float4*)src)[1];
        uint4 o = make_uint4(pk2(fa.x, fa.y), pk2(fa.z, fa.w), pk2(fb.x, fb.y), pk2(fb.z, fb.w));
        *(uint4*)(Bfrag + ((size_t)bid * 64 + l) * 8) = o;
    } else {
        __shared__ int sr_s[4], sw_s[4];
        const int t = threadIdx.x;
        const int4* r4 = (const int4*)ri;
        const int4* w4 = (const int4*)wi;
        int sr = 0, sw = 0;
        #pragma unroll 4
        for (int p = 0; p < 16; ++p) {
            int4 a = r4[p * 256 + t];
            int4 b = w4[p * 256 + t];
            sr += (a.x >= 1) + (a.y >= 1) + (a.z >= 1) + (a.w >= 1);
            sw += (b.x >= 1) + (b.y >= 1) + (b.z >= 1) + (b.w >= 1);
        }
        for (int off = 1; off < 64; off <<= 1) { sr += __shfl_xor(sr, off); sw += __shfl_xor(sw, off); }
        int wid = t >> 6;
        if ((t & 63) == 0) { sr_s[wid] = sr; sw_s[wid] = sw; }
        __syncthreads();
        if (t == 0) {
            int SR = sr_s[0]+sr_s[1]+sr_s[2]+sr_s[3];
            int SW = sw_s[0]+sw_s[1]+sw_s[2]+sw_s[3];
            sig[0] = 1.0f / (1.0f + __expf(-(float)SR));
            sig[1] = 1.0f / (1.0f + __expf(-(float)SW));
        }
    }
}

// ---------------- kernel 2: MFMA precompute -> E/A (bf16, [row][v]) + Wf (f32) / WT (f32) ----------------
__global__ __launch_bounds__(256) void k_mfma(
    const int* __restrict__ ri, const int* __restrict__ wi, const int* __restrict__ tgt,
    const float* __restrict__ q_emb, const float* __restrict__ i_emb,
    const float* __restrict__ erase_b, const float* __restrict__ add_b,
    const unsigned short* __restrict__ Bfrag,
    unsigned short* __restrict__ Ebuf, unsigned short* __restrict__ Abuf,
    float* __restrict__ Wf, float* __restrict__ WTbuf)
{
    __shared__ __align__(16) char shA[32 * 256];      // Xi bf16, swizzled
    __shared__ __align__(16) char shB[32 * 68 * 4];   // Xq bf16 swizzled, then logits f32 [32][68]
    __shared__ int id_s[32], ir_s[32];

    const int t = threadIdx.x;
    const int lane = t & 63;
    const int w = t >> 6;
    const int base = blockIdx.x * 32;
    const bool ea = (base < MROWS);

    if (t < 32) {
        int r = base + t;
        int irow = 0, qid;
        if (r < MROWS) {
            int m = r >> 14;
            int idx = r & 16383;
            int inter = (m == 0) ? ri[idx] : wi[idx];
            irow = inter;
            qid = (inter > QN) ? inter - QN : inter;
        } else {
            qid = tgt[r - MROWS];
        }
        id_s[t] = qid; ir_s[t] = irow;
    }
    __syncthreads();

    // stage Xq (always) and Xi (if E/A block), bf16 + XOR-swizzle (byte ^= (row&7)<<4)
    {
        const int r = t >> 3, o = t & 7;
        const int bb = r * 256 + o * 32;
        const int sw = (r & 7) << 4;
        {
            const float* src = q_emb + (size_t)id_s[r] * KD + o * 16;
            float4 f0 = ((const float4*)src)[0];
            float4 f1 = ((const float4*)src)[1];
            float4 f2 = ((const float4*)src)[2];
            float4 f3 = ((const float4*)src)[3];
            *(uint4*)(shB + (bb ^ sw))        = make_uint4(pk2(f0.x,f0.y), pk2(f0.z,f0.w), pk2(f1.x,f1.y), pk2(f1.z,f1.w));
            *(uint4*)(shB + ((bb + 16) ^ sw)) = make_uint4(pk2(f2.x,f2.y), pk2(f2.z,f2.w), pk2(f3.x,f3.y), pk2(f3.z,f3.w));
        }
        if (ea) {
            const float* src = i_emb + (size_t)ir_s[r] * KD + o * 16;
            float4 f0 = ((const float4*)src)[0];
            float4 f1 = ((const float4*)src)[1];
            float4 f2 = ((const float4*)src)[2];
            float4 f3 = ((const float4*)src)[3];
            *(uint4*)(shA + (bb ^ sw))        = make_uint4(pk2(f0.x,f0.y), pk2(f0.z,f0.w), pk2(f1.x,f1.y), pk2(f1.z,f1.w));
            *(uint4*)(shA + ((bb + 16) ^ sw)) = make_uint4(pk2(f2.x,f2.y), pk2(f2.z,f2.w), pk2(f3.x,f3.y), pk2(f3.z,f3.w));
        }
    }
    __syncthreads();

    // ---- key logits GEMM: Xq(32x128) x key_W^T(128x64), wave w owns cols w*16..w*16+15 ----
    const int rowl = lane & 15;
    const int kb16 = (lane >> 4) * 16;

    bf16x8 afQ[2][4];
    #pragma unroll
    for (int mt = 0; mt < 2; ++mt)
        #pragma unroll
        for (int kt = 0; kt < 4; ++kt) {
            int row = mt * 16 + rowl;
            int addr = (row * 256 + kt * 64 + kb16) ^ ((row & 7) << 4);
            afQ[mt][kt] = *(const bf16x8*)(shB + addr);
        }

    f32x4 accK0 = {0.f,0.f,0.f,0.f}, accK1 = {0.f,0.f,0.f,0.f};
    {
        const int gk = 16 + w;
        #pragma unroll
        for (int kt = 0; kt < 4; ++kt) {
            bf16x8 bf = *(const bf16x8*)(Bfrag + ((size_t)(gk * 4 + kt) * 64 + lane) * 8);
            accK0 = __builtin_amdgcn_mfma_f32_16x16x32_bf16(afQ[0][kt], bf, accK0, 0, 0, 0);
            accK1 = __builtin_amdgcn_mfma_f32_16x16x32_bf16(afQ[1][kt], bf, accK1, 0, 0, 0);
        }
    }
    __syncthreads();   // done reading shB (Xq)

    // write logits to shB as f32 [32][68]
    {
        float* L = (float*)shB;
        const int col = w * 16 + rowl;
        const int rb4 = (lane >> 4) * 4;
        #pragma unroll
        for (int rr = 0; rr < 4; ++rr) L[(rb4 + rr) * 68 + col] = accK0[rr];
        #pragma unroll
        for (int rr = 0; rr < 4; ++rr) L[(16 + rb4 + rr) * 68 + col] = accK1[rr];
    }
    __syncthreads();

    // softmax over 64 cols: 8 threads per row, shfl-reduce in 8-lane groups
    {
        const float* L = (const float*)shB;
        const int rr = t >> 3, q = t & 7;
        float4 va = *(const float4*)(L + rr * 68 + q * 8);
        float4 vb = *(const float4*)(L + rr * 68 + q * 8 + 4);
        float mx = fmaxf(fmaxf(fmaxf(va.x, va.y), fmaxf(va.z, va.w)),
                         fmaxf(fmaxf(vb.x, vb.y), fmaxf(vb.z, vb.w)));
        #pragma unroll
        for (int off = 1; off < 8; off <<= 1) mx = fmaxf(mx, __shfl_xor(mx, off));
        float e0 = __expf(va.x - mx), e1 = __expf(va.y - mx), e2 = __expf(va.z - mx), e3 = __expf(va.w - mx);
        float e4 = __expf(vb.x - mx), e5 = __expf(vb.y - mx), e6 = __expf(vb.z - mx), e7 = __expf(vb.w - mx);
        float s = e0 + e1 + e2 + e3 + e4 + e5 + e6 + e7;
        #pragma unroll
        for (int off = 1; off < 8; off <<= 1) s += __shfl_xor(s, off);
        float inv = 1.0f / s;
        int R = base + rr;
        if (R < MROWS) {
            float* dw = Wf + (size_t)R * CN + q * 8;
            *(float4*)dw       = make_float4(e0*inv, e1*inv, e2*inv, e3*inv);
            *(float4*)(dw + 4) = make_float4(e4*inv, e5*inv, e6*inv, e7*inv);
        } else {
            float* dst = WTbuf + (size_t)(R - MROWS) * CN + q * 8;
            *(float4*)dst       = make_float4(e0*inv, e1*inv, e2*inv, e3*inv);
            *(float4*)(dst + 4) = make_float4(e4*inv, e5*inv, e6*inv, e7*inv);
        }
    }

    // ---- E/A GEMM: Xi(32x128) x [erase;add]^T(128x256); wave w owns g = w, w+4, w+8, w+12 ----
    if (ea) {
        bf16x8 afI[2][4];
        #pragma unroll
        for (int mt = 0; mt < 2; ++mt)
            #pragma unroll
            for (int kt = 0; kt < 4; ++kt) {
                int row = mt * 16 + rowl;
                int addr = (row * 256 + kt * 64 + kb16) ^ ((row & 7) << 4);
                afI[mt][kt] = *(const bf16x8*)(shA + addr);
            }

        const int rb4 = (lane >> 4) * 4;
        #pragma unroll
        for (int gi = 0; gi < 4; ++gi) {
            const int g = w + gi * 4;            // 0..15
            f32x4 a0 = {0.f,0.f,0.f,0.f}, a1 = {0.f,0.f,0.f,0.f};
            #pragma unroll
            for (int kt = 0; kt < 4; ++kt) {
                bf16x8 bf = *(const bf16x8*)(Bfrag + ((size_t)(g * 4 + kt) * 64 + lane) * 8);
                a0 = __builtin_amdgcn_mfma_f32_16x16x32_bf16(afI[0][kt], bf, a0, 0, 0, 0);
                a1 = __builtin_amdgcn_mfma_f32_16x16x32_bf16(afI[1][kt], bf, a1, 0, 0, 0);
            }
            const bool isE = (g < 8);
            const int cc = (g & 7) * 16 + rowl;  // col within E or A (0..127) == v
            const float bv = isE ? erase_b[cc] : add_b[cc];
            unsigned short* dst = isE ? Ebuf : Abuf;
            #pragma unroll
            for (int mt = 0; mt < 2; ++mt) {
                f32x4 av = mt ? a1 : a0;
                #pragma unroll
                for (int rr = 0; rr < 4; ++rr) {
                    float x = av[rr] + bv;
                    float y = isE ? fast_sig(x) : fast_tanh(x);
                    dst[(size_t)(base + mt * 16 + rb4 + rr) * VD + cc] = f2bf(y);
                }
            }
        }
    }
}

// ---------------- kernel 3: scan with LDS-staged E/A (coalesced [s][v] tiles) ----------------
__global__ __launch_bounds__(1024, 8) void k_scan(
    const unsigned short* __restrict__ Ebuf, const unsigned short* __restrict__ Abuf,
    const float* __restrict__ Wf, const float* __restrict__ WTbuf,
    const float* __restrict__ rmem0, const float* __restrict__ wmem0,
    float* __restrict__ readbuf)
{
    __shared__ unsigned short lds_e[SS * VD];   // 32 KB
    __shared__ unsigned short lds_a[SS * VD];   // 32 KB
    __shared__ float psum[8 * 128];             //  4 KB
    const int t  = threadIdx.x;
    const int chain = blockIdx.x;       // m*BB + b
    const int m  = chain >> 7;
    const int b  = chain & 127;
    const int ck = t >> 7;              // 0..7  (wave-uniform)
    const int v  = t & 127;
    const int c0 = ck * 8;

    // stage E/A tiles (contiguous 32 KB each) into LDS, fully coalesced
    {
        const uint4* sE = (const uint4*)(Ebuf + (size_t)chain * SS * VD);
        const uint4* sA = (const uint4*)(Abuf + (size_t)chain * SS * VD);
        uint4* dE = (uint4*)lds_e;
        uint4* dA = (uint4*)lds_a;
        dE[t] = sE[t]; dE[t + 1024] = sE[t + 1024];
        dA[t] = sA[t]; dA[t + 1024] = sA[t + 1024];
    }

    const float* minit = (m == 0) ? rmem0 : wmem0;
    f32x2 mm[4];
    #pragma unroll
    for (int j = 0; j < 4; ++j) {
        mm[j].x = minit[v * CN + c0 + 2*j];
        mm[j].y = minit[v * CN + c0 + 2*j + 1];
    }
    __syncthreads();

    const float* Wp = Wf + (size_t)chain * SS * CN + c0;

    #pragma unroll 8
    for (int s = 0; s < SS; ++s) {
        float e = bflo((unsigned int)lds_e[s * VD + v]);
        float a = bflo((unsigned int)lds_a[s * VD + v]);
        float4 w0 = *(const float4*)(Wp + (size_t)s * CN);      // wave-uniform broadcast
        float4 w1 = *(const float4*)(Wp + (size_t)s * CN + 4);
        f32x2 ev = {e, e}, av = {a, a}, g, wv;
        g = av - ev * mm[0]; wv.x = w0.x; wv.y = w0.y; mm[0] += wv * g;
        g = av - ev * mm[1]; wv.x = w0.z; wv.y = w0.w; mm[1] += wv * g;
        g = av - ev * mm[2]; wv.x = w1.x; wv.y = w1.y; mm[2] += wv * g;
        g = av - ev * mm[3]; wv.x = w1.z; wv.y = w1.w; mm[3] += wv * g;
    }

    const float* wt = WTbuf + (size_t)b * CN + c0;
    float4 wa = *(const float4*)wt;
    float4 wb = *(const float4*)(wt + 4);
    float p = 0.0f;
    p = fmaf(mm[0].x, wa.x, p); p = fmaf(mm[0].y, wa.y, p);
    p = fmaf(mm[1].x, wa.z, p); p = fmaf(mm[1].y, wa.w, p);
    p = fmaf(mm[2].x, wb.x, p); p = fmaf(mm[2].y, wb.y, p);
    p = fmaf(mm[3].x, wb.z, p); p = fmaf(mm[3].y, wb.w, p);
    psum[ck * 128 + v] = p;
    __syncthreads();
    if (t < 128) {
        float s = 0.0f;
        #pragma unroll
        for (int j = 0; j < 8; ++j) s += psum[j * 128 + t];
        readbuf[(size_t)chain * VD + t] = s;
    }
}

// ---------------- kernel 4: head (256 threads, k-split) ----------------
__global__ __launch_bounds__(256) void k_head(
    const float* __restrict__ readbuf, const int* __restrict__ tgt,
    const float* __restrict__ q_emb,
    const float* __restrict__ rsum_W, const float* __restrict__ rsum_b,
    const float* __restrict__ wsum_W, const float* __restrict__ wsum_b,
    const float* __restrict__ succ_W, const float* __restrict__ succ_b,
    const float* __restrict__ fail_W, const float* __restrict__ fail_b,
    const float* __restrict__ diff_W, const float* __restrict__ diff_b,
    const float* __restrict__ sig, float* __restrict__ out)
{
    __shared__ float xr[256], xw[256];
    __shared__ float part[2][128];
    __shared__ float red_s[6];
    const int t = threadIdx.x;
    const int j = t & 127;
    const int h = t >> 7;
    const int b = blockIdx.x;
    if (h == 0) {
        int tid_ = tgt[b];
        float qv = q_emb[(size_t)tid_ * KD + j];
        xr[j]       = readbuf[(size_t)b * VD + j];
        xr[128 + j] = qv;
        xw[j]       = readbuf[(size_t)(BB + b) * VD + j];
        xw[128 + j] = qv;
    }
    __syncthreads();

    float rs = (h == 0) ? rsum_b[j] : 0.0f;
    float wv = (h == 0) ? wsum_b[j] : 0.0f;
    const float* rw = rsum_W + (size_t)j * 256 + h * 128;
    const float* ww = wsum_W + (size_t)j * 256 + h * 128;
    const float* xrp = xr + h * 128;
    const float* xwp = xw + h * 128;
    #pragma unroll 4
    for (int k = 0; k < 128; ++k) {
        rs = fmaf(rw[k], xrp[k], rs);
        wv = fmaf(ww[k], xwp[k], wv);
    }
    if (h == 1) { part[0][j] = rs; part[1][j] = wv; }
    __syncthreads();
    if (h == 0) {
        rs += part[0][j];
        wv += part[1][j];
        float r_sum = fast_tanh(rs), w_sum = fast_tanh(wv);
        float qv = xr[128 + j];
        float ps = r_sum * succ_W[j];
        float pf = w_sum * fail_W[j];
        float pd = qv    * diff_W[j];
        for (int off = 1; off < 64; off <<= 1) {
            ps += __shfl_xor(ps, off);
            pf += __shfl_xor(pf, off);
            pd += __shfl_xor(pd, off);
        }
        int wid = j >> 6;
        if ((j & 63) == 0) { red_s[wid*3+0] = ps; red_s[wid*3+1] = pf; red_s[wid*3+2] = pd; }
    }
    __syncthreads();
    if (t == 0) {
        float Ps = red_s[0] + red_s[3];
        float Pf = red_s[1] + red_s[4];
        float Pd = red_s[2] + red_s[5];
        float succ = fast_tanh(Ps + succ_b[0]);
        float fail = fast_tanh(Pf + fail_b[0]);
        float diff = fast_tanh(Pd + diff_b[0]);
        out[b] = succ * sig[0] + fail * sig[1] - 2.0f * diff;
    }
}

extern "C" void kernel_launch(void* const* d_in, const int* in_sizes, int n_in,
                              void* d_out, int out_size, void* d_ws, size_t ws_size,
                              hipStream_t stream) {
    const int*   ri      = (const int*)d_in[0];
    const int*   wi      = (const int*)d_in[1];
    const int*   tgt     = (const int*)d_in[2];
    const float* q_emb   = (const float*)d_in[3];
    const float* i_emb   = (const float*)d_in[4];
    const float* key_W   = (const float*)d_in[5];
    const float* erase_W = (const float*)d_in[6];
    const float* erase_b = (const float*)d_in[7];
    const float* add_W   = (const float*)d_in[8];
    const float* add_b   = (const float*)d_in[9];
    const float* rsum_W  = (const float*)d_in[10];
    const float* rsum_b  = (const float*)d_in[11];
    const float* wsum_W  = (const float*)d_in[12];
    const float* wsum_b  = (const float*)d_in[13];
    const float* succ_W  = (const float*)d_in[14];
    const float* succ_b  = (const float*)d_in[15];
    const float* fail_W  = (const float*)d_in[16];
    const float* fail_b  = (const float*)d_in[17];
    const float* diff_W  = (const float*)d_in[18];
    const float* diff_b  = (const float*)d_in[19];
    const float* rmem0   = (const float*)d_in[20];
    const float* wmem0   = (const float*)d_in[21];

    char* ws = (char*)d_ws;
    unsigned short* Ebuf    = (unsigned short*)(ws + 0);          //  8,388,608 B
    unsigned short* Abuf    = (unsigned short*)(ws + 8388608);    //  8,388,608 B
    float*          Wf      = (float*)(ws + 16777216);            //  8,388,608 B
    float*          WTbuf   = (float*)(ws + 25165824);            //     32,768 B
    float*          readbuf = (float*)(ws + 25198592);            //    131,072 B
    unsigned short* Bfrag   = (unsigned short*)(ws + 25329664);   //     81,920 B
    float*          sig     = (float*)(ws + 25411584);            //          8 B
    float*          out     = (float*)d_out;

    hipLaunchKernelGGL(k_wcnt, dim3(21), dim3(256), 0, stream,
        erase_W, add_W, key_W, Bfrag, ri, wi, sig);
    hipLaunchKernelGGL(k_mfma, dim3(1028), dim3(256), 0, stream,
        ri, wi, tgt, q_emb, i_emb, erase_b, add_b, Bfrag,
        Ebuf, Abuf, Wf, WTbuf);
    hipLaunchKernelGGL(k_scan, dim3(256), dim3(1024), 0, stream,
        Ebuf, Abuf, Wf, WTbuf, rmem0, wmem0, readbuf);
    hipLaunchKernelGGL(k_head, dim3(128), dim3(256), 0, stream,
        readbuf, tgt, q_emb, rsum_W, rsum_b, wsum_W, wsum_b,
        succ_W, succ_b, fail_W, fail_b, diff_W, diff_b, sig, out);
}

// Round 5
// 61.385 us; speedup vs baseline: 1.4142x; 1.2554x over previous
//
#include <hip/hip_runtime.h>
#include <hip/hip_bf16.h>

#define BB 128      // batch
#define SS 128      // seq len
#define VD 128      // VALUE_DIM
#define CN 64       // CONCEPT_NUM
#define KD 128      // KEY_DIM
#define QN 10000
#define MROWS (2*BB*SS)       // 32768
#define MTOT  (MROWS + BB)    // 32896

typedef __attribute__((ext_vector_type(8))) short bf16x8;
typedef __attribute__((ext_vector_type(4))) float f32x4;
typedef __attribute__((ext_vector_type(2))) float f32x2;

__device__ __forceinline__ float bflo(unsigned int u) { return __uint_as_float(u << 16); }
__device__ __forceinline__ float bfhi(unsigned int u) { return __uint_as_float(u & 0xffff0000u); }
__device__ __forceinline__ unsigned short f2bf(float f) {
    unsigned int x = __float_as_uint(f);
    return (unsigned short)((x + 0x7fffu + ((x >> 16) & 1u)) >> 16);
}
__device__ __forceinline__ unsigned int pk2(float lo, float hi) {
    return (unsigned int)f2bf(lo) | ((unsigned int)f2bf(hi) << 16);
}
__device__ __forceinline__ float fast_tanh(float x) {
    float e = __expf(2.0f * x);
    return 1.0f - 2.0f / (e + 1.0f);
}
__device__ __forceinline__ float fast_sig(float x) {
    return 1.0f / (1.0f + __expf(-x));
}

// ---------------- kernel 1: weight pack (blocks 0..19) + counts (block 20) ----------------
__global__ __launch_bounds__(256) void k_wcnt(
    const float* __restrict__ erase_W, const float* __restrict__ add_W,
    const float* __restrict__ key_W, unsigned short* __restrict__ Bfrag,
    const int* __restrict__ ri, const int* __restrict__ wi, float* __restrict__ sig)
{
    if (blockIdx.x < 20) {
        const int bid = blockIdx.x * 4 + (threadIdx.x >> 6);   // 0..79
        const int l = threadIdx.x & 63;
        const int n = (bid >> 2) * 16 + (l & 15);
        const int k0 = (bid & 3) * 32 + (l >> 4) * 8;
        const float* src;
        if (n < 128)      src = erase_W + (size_t)n * KD + k0;
        else if (n < 256) src = add_W + (size_t)(n - 128) * KD + k0;
        else              src = key_W + (size_t)(n - 256) * KD + k0;
        float4 fa = ((const float4*)src)[0];
        float4 fb = ((const float4*)src)[1];
        uint4 o = make_uint4(pk2(fa.x, fa.y), pk2(fa.z, fa.w), pk2(fb.x, fb.y), pk2(fb.z, fb.w));
        *(uint4*)(Bfrag + ((size_t)bid * 64 + l) * 8) = o;
    } else {
        __shared__ int sr_s[4], sw_s[4];
        const int t = threadIdx.x;
        const int4* r4 = (const int4*)ri;
        const int4* w4 = (const int4*)wi;
        int sr = 0, sw = 0;
        #pragma unroll 4
        for (int p = 0; p < 16; ++p) {
            int4 a = r4[p * 256 + t];
            int4 b = w4[p * 256 + t];
            sr += (a.x >= 1) + (a.y >= 1) + (a.z >= 1) + (a.w >= 1);
            sw += (b.x >= 1) + (b.y >= 1) + (b.z >= 1) + (b.w >= 1);
        }
        for (int off = 1; off < 64; off <<= 1) { sr += __shfl_xor(sr, off); sw += __shfl_xor(sw, off); }
        int wid = t >> 6;
        if ((t & 63) == 0) { sr_s[wid] = sr; sw_s[wid] = sw; }
        __syncthreads();
        if (t == 0) {
            int SR = sr_s[0]+sr_s[1]+sr_s[2]+sr_s[3];
            int SW = sw_s[0]+sw_s[1]+sw_s[2]+sw_s[3];
            sig[0] = 1.0f / (1.0f + __expf(-(float)SR));
            sig[1] = 1.0f / (1.0f + __expf(-(float)SW));
        }
    }
}

// ---------------- kernel 2: MFMA precompute -> EA (bf16 pairs, [row][v]) + Wf (f32) / WT (f32) ----------------
__global__ __launch_bounds__(256) void k_mfma(
    const int* __restrict__ ri, const int* __restrict__ wi, const int* __restrict__ tgt,
    const float* __restrict__ q_emb, const float* __restrict__ i_emb,
    const float* __restrict__ erase_b, const float* __restrict__ add_b,
    const unsigned short* __restrict__ Bfrag,
    unsigned short* __restrict__ EAbuf,
    float* __restrict__ Wf, float* __restrict__ WTbuf)
{
    __shared__ __align__(16) char shA[32 * 256];      // Xi bf16, swizzled
    __shared__ __align__(16) char shB[32 * 68 * 4];   // Xq bf16 swizzled, then logits f32 [32][68]
    __shared__ int id_s[32], ir_s[32];

    const int t = threadIdx.x;
    const int lane = t & 63;
    const int w = t >> 6;
    const int base = blockIdx.x * 32;
    const bool ea = (base < MROWS);

    if (t < 32) {
        int r = base + t;
        int irow = 0, qid;
        if (r < MROWS) {
            int m = r >> 14;
            int idx = r & 16383;
            int inter = (m == 0) ? ri[idx] : wi[idx];
            irow = inter;
            qid = (inter > QN) ? inter - QN : inter;
        } else {
            qid = tgt[r - MROWS];
        }
        id_s[t] = qid; ir_s[t] = irow;
    }
    __syncthreads();

    // stage Xq (always) and Xi (if E/A block), bf16 + XOR-swizzle (byte ^= (row&7)<<4)
    {
        const int r = t >> 3, o = t & 7;
        const int bb = r * 256 + o * 32;
        const int sw = (r & 7) << 4;
        {
            const float* src = q_emb + (size_t)id_s[r] * KD + o * 16;
            float4 f0 = ((const float4*)src)[0];
            float4 f1 = ((const float4*)src)[1];
            float4 f2 = ((const float4*)src)[2];
            float4 f3 = ((const float4*)src)[3];
            *(uint4*)(shB + (bb ^ sw))        = make_uint4(pk2(f0.x,f0.y), pk2(f0.z,f0.w), pk2(f1.x,f1.y), pk2(f1.z,f1.w));
            *(uint4*)(shB + ((bb + 16) ^ sw)) = make_uint4(pk2(f2.x,f2.y), pk2(f2.z,f2.w), pk2(f3.x,f3.y), pk2(f3.z,f3.w));
        }
        if (ea) {
            const float* src = i_emb + (size_t)ir_s[r] * KD + o * 16;
            float4 f0 = ((const float4*)src)[0];
            float4 f1 = ((const float4*)src)[1];
            float4 f2 = ((const float4*)src)[2];
            float4 f3 = ((const float4*)src)[3];
            *(uint4*)(shA + (bb ^ sw))        = make_uint4(pk2(f0.x,f0.y), pk2(f0.z,f0.w), pk2(f1.x,f1.y), pk2(f1.z,f1.w));
            *(uint4*)(shA + ((bb + 16) ^ sw)) = make_uint4(pk2(f2.x,f2.y), pk2(f2.z,f2.w), pk2(f3.x,f3.y), pk2(f3.z,f3.w));
        }
    }
    __syncthreads();

    // ---- key logits GEMM: Xq(32x128) x key_W^T(128x64), wave w owns cols w*16..w*16+15 ----
    const int rowl = lane & 15;
    const int kb16 = (lane >> 4) * 16;

    bf16x8 afQ[2][4];
    #pragma unroll
    for (int mt = 0; mt < 2; ++mt)
        #pragma unroll
        for (int kt = 0; kt < 4; ++kt) {
            int row = mt * 16 + rowl;
            int addr = (row * 256 + kt * 64 + kb16) ^ ((row & 7) << 4);
            afQ[mt][kt] = *(const bf16x8*)(shB + addr);
        }

    f32x4 accK0 = {0.f,0.f,0.f,0.f}, accK1 = {0.f,0.f,0.f,0.f};
    {
        const int gk = 16 + w;
        #pragma unroll
        for (int kt = 0; kt < 4; ++kt) {
            bf16x8 bf = *(const bf16x8*)(Bfrag + ((size_t)(gk * 4 + kt) * 64 + lane) * 8);
            accK0 = __builtin_amdgcn_mfma_f32_16x16x32_bf16(afQ[0][kt], bf, accK0, 0, 0, 0);
            accK1 = __builtin_amdgcn_mfma_f32_16x16x32_bf16(afQ[1][kt], bf, accK1, 0, 0, 0);
        }
    }
    __syncthreads();   // done reading shB (Xq)

    // write logits to shB as f32 [32][68]
    {
        float* L = (float*)shB;
        const int col = w * 16 + rowl;
        const int rb4 = (lane >> 4) * 4;
        #pragma unroll
        for (int rr = 0; rr < 4; ++rr) L[(rb4 + rr) * 68 + col] = accK0[rr];
        #pragma unroll
        for (int rr = 0; rr < 4; ++rr) L[(16 + rb4 + rr) * 68 + col] = accK1[rr];
    }
    __syncthreads();

    // softmax over 64 cols: 8 threads per row, shfl-reduce in 8-lane groups
    {
        const float* L = (const float*)shB;
        const int rr = t >> 3, q = t & 7;
        float4 va = *(const float4*)(L + rr * 68 + q * 8);
        float4 vb = *(const float4*)(L + rr * 68 + q * 8 + 4);
        float mx = fmaxf(fmaxf(fmaxf(va.x, va.y), fmaxf(va.z, va.w)),
                         fmaxf(fmaxf(vb.x, vb.y), fmaxf(vb.z, vb.w)));
        #pragma unroll
        for (int off = 1; off < 8; off <<= 1) mx = fmaxf(mx, __shfl_xor(mx, off));
        float e0 = __expf(va.x - mx), e1 = __expf(va.y - mx), e2 = __expf(va.z - mx), e3 = __expf(va.w - mx);
        float e4 = __expf(vb.x - mx), e5 = __expf(vb.y - mx), e6 = __expf(vb.z - mx), e7 = __expf(vb.w - mx);
        float s = e0 + e1 + e2 + e3 + e4 + e5 + e6 + e7;
        #pragma unroll
        for (int off = 1; off < 8; off <<= 1) s += __shfl_xor(s, off);
        float inv = 1.0f / s;
        int R = base + rr;
        if (R < MROWS) {
            float* dw = Wf + (size_t)R * CN + q * 8;
            *(float4*)dw       = make_float4(e0*inv, e1*inv, e2*inv, e3*inv);
            *(float4*)(dw + 4) = make_float4(e4*inv, e5*inv, e6*inv, e7*inv);
        } else {
            float* dst = WTbuf + (size_t)(R - MROWS) * CN + q * 8;
            *(float4*)dst       = make_float4(e0*inv, e1*inv, e2*inv, e3*inv);
            *(float4*)(dst + 4) = make_float4(e4*inv, e5*inv, e6*inv, e7*inv);
        }
    }

    // ---- E/A GEMM: Xi(32x128) x [erase;add]^T(128x256); wave w owns g = w, w+4, w+8, w+12 ----
    // Epilogue writes INTERLEAVED pairs: EA[(row*VD + v)*2 + {0:e, 1:a}]
    if (ea) {
        bf16x8 afI[2][4];
        #pragma unroll
        for (int mt = 0; mt < 2; ++mt)
            #pragma unroll
            for (int kt = 0; kt < 4; ++kt) {
                int row = mt * 16 + rowl;
                int addr = (row * 256 + kt * 64 + kb16) ^ ((row & 7) << 4);
                afI[mt][kt] = *(const bf16x8*)(shA + addr);
            }

        const int rb4 = (lane >> 4) * 4;
        #pragma unroll
        for (int gi = 0; gi < 4; ++gi) {
            const int g = w + gi * 4;            // 0..15
            f32x4 a0 = {0.f,0.f,0.f,0.f}, a1 = {0.f,0.f,0.f,0.f};
            #pragma unroll
            for (int kt = 0; kt < 4; ++kt) {
                bf16x8 bf = *(const bf16x8*)(Bfrag + ((size_t)(g * 4 + kt) * 64 + lane) * 8);
                a0 = __builtin_amdgcn_mfma_f32_16x16x32_bf16(afI[0][kt], bf, a0, 0, 0, 0);
                a1 = __builtin_amdgcn_mfma_f32_16x16x32_bf16(afI[1][kt], bf, a1, 0, 0, 0);
            }
            const bool isE = (g < 8);
            const int cc = (g & 7) * 16 + rowl;  // col within E or A (0..127) == v
            const float bv = isE ? erase_b[cc] : add_b[cc];
            const int off = isE ? 0 : 1;
            #pragma unroll
            for (int mt = 0; mt < 2; ++mt) {
                f32x4 av = mt ? a1 : a0;
                #pragma unroll
                for (int rr = 0; rr < 4; ++rr) {
                    float x = av[rr] + bv;
                    float y = isE ? fast_sig(x) : fast_tanh(x);
                    EAbuf[((size_t)(base + mt * 16 + rb4 + rr) * VD + cc) * 2 + off] = f2bf(y);
                }
            }
        }
    }
}

// ---------------- kernel 3: scan, all-LDS inner loop, 2 blocks/CU ----------------
// grid 512: block = (chalf, chain). 512 threads = (ck2 0..3) x (v 0..127).
__global__ __launch_bounds__(512, 4) void k_scan(
    const unsigned int* __restrict__ EAbuf, const float* __restrict__ Wf,
    const float* __restrict__ WTbuf,
    const float* __restrict__ rmem0, const float* __restrict__ wmem0,
    float* __restrict__ readbuf)
{
    __shared__ unsigned int lds_ea[SS * VD];   // 64 KB: {e,a} bf16 pair per u32
    __shared__ float lds_w[SS * 32];           // 16 KB: this block's c-half; reused as psum
    const int t = threadIdx.x;
    const int chain = blockIdx.x & 255;        // m*BB + b
    const int chalf = blockIdx.x >> 8;         // 0..1
    const int m  = chain >> 7;
    const int b  = chain & 127;
    const int ck2 = t >> 7;                    // 0..3 (wave-uniform)
    const int v  = t & 127;
    const int c0l = ck2 * 8;                   // local c within the 32-half

    // stage EA (64 KB contiguous) and W half (rows of 128 B, stride 256 B)
    {
        const uint4* sEA = (const uint4*)(EAbuf + (size_t)chain * SS * VD);
        uint4* dEA = (uint4*)lds_ea;
        #pragma unroll
        for (int i = 0; i < 8; ++i) dEA[t + i * 512] = sEA[t + i * 512];
        const float* sW = Wf + (size_t)chain * SS * CN + chalf * 32;
        float4* dW = (float4*)lds_w;
        #pragma unroll
        for (int i = 0; i < 2; ++i) {
            int idx = t + i * 512;
            int s = idx >> 3, q = idx & 7;
            dW[idx] = *(const float4*)(sW + (size_t)s * CN + q * 4);
        }
    }

    const float* minit = (m == 0) ? rmem0 : wmem0;
    f32x2 mm[4];
    #pragma unroll
    for (int j = 0; j < 4; ++j) {
        mm[j].x = minit[v * CN + chalf * 32 + c0l + 2*j];
        mm[j].y = minit[v * CN + chalf * 32 + c0l + 2*j + 1];
    }
    __syncthreads();

    #pragma unroll 8
    for (int s = 0; s < SS; ++s) {
        unsigned int u = lds_ea[s * VD + v];
        float e = bflo(u), a = bfhi(u);
        const float* wp = lds_w + s * 32 + c0l;
        float4 w0 = *(const float4*)wp;          // broadcast (wave-uniform addr)
        float4 w1 = *(const float4*)(wp + 4);
        f32x2 ev = {e, e}, av = {a, a}, g, wv;
        g = av - ev * mm[0]; wv.x = w0.x; wv.y = w0.y; mm[0] += wv * g;
        g = av - ev * mm[1]; wv.x = w0.z; wv.y = w0.w; mm[1] += wv * g;
        g = av - ev * mm[2]; wv.x = w1.x; wv.y = w1.y; mm[2] += wv * g;
        g = av - ev * mm[3]; wv.x = w1.z; wv.y = w1.w; mm[3] += wv * g;
    }

    const float* wt = WTbuf + (size_t)b * CN + chalf * 32 + c0l;
    float4 wa = *(const float4*)wt;
    float4 wb = *(const float4*)(wt + 4);
    float p = 0.0f;
    p = fmaf(mm[0].x, wa.x, p); p = fmaf(mm[0].y, wa.y, p);
    p = fmaf(mm[1].x, wa.z, p); p = fmaf(mm[1].y, wa.w, p);
    p = fmaf(mm[2].x, wb.x, p); p = fmaf(mm[2].y, wb.y, p);
    p = fmaf(mm[3].x, wb.z, p); p = fmaf(mm[3].y, wb.w, p);
    __syncthreads();                 // done with lds_w as W; reuse as psum
    lds_w[ck2 * 128 + v] = p;
    __syncthreads();
    if (t < 128) {
        float s = lds_w[t] + lds_w[128 + t] + lds_w[256 + t] + lds_w[384 + t];
        readbuf[((size_t)chalf * 256 + chain) * VD + t] = s;
    }
}

// ---------------- kernel 4: head (256 threads, k-split; sums the two c-half partials) ----------------
__global__ __launch_bounds__(256) void k_head(
    const float* __restrict__ readbuf, const int* __restrict__ tgt,
    const float* __restrict__ q_emb,
    const float* __restrict__ rsum_W, const float* __restrict__ rsum_b,
    const float* __restrict__ wsum_W, const float* __restrict__ wsum_b,
    const float* __restrict__ succ_W, const float* __restrict__ succ_b,
    const float* __restrict__ fail_W, const float* __restrict__ fail_b,
    const float* __restrict__ diff_W, const float* __restrict__ diff_b,
    const float* __restrict__ sig, float* __restrict__ out)
{
    __shared__ float xr[256], xw[256];
    __shared__ float part[2][128];
    __shared__ float red_s[6];
    const int t = threadIdx.x;
    const int j = t & 127;
    const int h = t >> 7;
    const int b = blockIdx.x;
    if (h == 0) {
        int tid_ = tgt[b];
        float qv = q_emb[(size_t)tid_ * KD + j];
        xr[j]       = readbuf[(size_t)b * VD + j] + readbuf[(size_t)(256 + b) * VD + j];
        xr[128 + j] = qv;
        xw[j]       = readbuf[(size_t)(BB + b) * VD + j] + readbuf[(size_t)(256 + BB + b) * VD + j];
        xw[128 + j] = qv;
    }
    __syncthreads();

    float rs = (h == 0) ? rsum_b[j] : 0.0f;
    float wv = (h == 0) ? wsum_b[j] : 0.0f;
    const float* rw = rsum_W + (size_t)j * 256 + h * 128;
    const float* ww = wsum_W + (size_t)j * 256 + h * 128;
    const float* xrp = xr + h * 128;
    const float* xwp = xw + h * 128;
    #pragma unroll 4
    for (int k = 0; k < 128; ++k) {
        rs = fmaf(rw[k], xrp[k], rs);
        wv = fmaf(ww[k], xwp[k], wv);
    }
    if (h == 1) { part[0][j] = rs; part[1][j] = wv; }
    __syncthreads();
    if (h == 0) {
        rs += part[0][j];
        wv += part[1][j];
        float r_sum = fast_tanh(rs), w_sum = fast_tanh(wv);
        float qv = xr[128 + j];
        float ps = r_sum * succ_W[j];
        float pf = w_sum * fail_W[j];
        float pd = qv    * diff_W[j];
        for (int off = 1; off < 64; off <<= 1) {
            ps += __shfl_xor(ps, off);
            pf += __shfl_xor(pf, off);
            pd += __shfl_xor(pd, off);
        }
        int wid = j >> 6;
        if ((j & 63) == 0) { red_s[wid*3+0] = ps; red_s[wid*3+1] = pf; red_s[wid*3+2] = pd; }
    }
    __syncthreads();
    if (t == 0) {
        float Ps = red_s[0] + red_s[3];
        float Pf = red_s[1] + red_s[4];
        float Pd = red_s[2] + red_s[5];
        float succ = fast_tanh(Ps + succ_b[0]);
        float fail = fast_tanh(Pf + fail_b[0]);
        float diff = fast_tanh(Pd + diff_b[0]);
        out[b] = succ * sig[0] + fail * sig[1] - 2.0f * diff;
    }
}

extern "C" void kernel_launch(void* const* d_in, const int* in_sizes, int n_in,
                              void* d_out, int out_size, void* d_ws, size_t ws_size,
                              hipStream_t stream) {
    const int*   ri      = (const int*)d_in[0];
    const int*   wi      = (const int*)d_in[1];
    const int*   tgt     = (const int*)d_in[2];
    const float* q_emb   = (const float*)d_in[3];
    const float* i_emb   = (const float*)d_in[4];
    const float* key_W   = (const float*)d_in[5];
    const float* erase_W = (const float*)d_in[6];
    const float* erase_b = (const float*)d_in[7];
    const float* add_W   = (const float*)d_in[8];
    const float* add_b   = (const float*)d_in[9];
    const float* rsum_W  = (const float*)d_in[10];
    const float* rsum_b  = (const float*)d_in[11];
    const float* wsum_W  = (const float*)d_in[12];
    const float* wsum_b  = (const float*)d_in[13];
    const float* succ_W  = (const float*)d_in[14];
    const float* succ_b  = (const float*)d_in[15];
    const float* fail_W  = (const float*)d_in[16];
    const float* fail_b  = (const float*)d_in[17];
    const float* diff_W  = (const float*)d_in[18];
    const float* diff_b  = (const float*)d_in[19];
    const float* rmem0   = (const float*)d_in[20];
    const float* wmem0   = (const float*)d_in[21];

    char* ws = (char*)d_ws;
    unsigned short* EAbuf   = (unsigned short*)(ws + 0);          // 16,777,216 B
    float*          Wf      = (float*)(ws + 16777216);            //  8,388,608 B
    float*          WTbuf   = (float*)(ws + 25165824);            //     32,768 B
    float*          readbuf = (float*)(ws + 25198592);            //    262,144 B (2 c-halves)
    unsigned short* Bfrag   = (unsigned short*)(ws + 25460736);   //     81,920 B
    float*          sig     = (float*)(ws + 25542656);            //          8 B
    float*          out     = (float*)d_out;

    hipLaunchKernelGGL(k_wcnt, dim3(21), dim3(256), 0, stream,
        erase_W, add_W, key_W, Bfrag, ri, wi, sig);
    hipLaunchKernelGGL(k_mfma, dim3(1028), dim3(256), 0, stream,
        ri, wi, tgt, q_emb, i_emb, erase_b, add_b, Bfrag,
        EAbuf, Wf, WTbuf);
    hipLaunchKernelGGL(k_scan, dim3(512), dim3(512), 0, stream,
        (const unsigned int*)EAbuf, Wf, WTbuf, rmem0, wmem0, readbuf);
    hipLaunchKernelGGL(k_head, dim3(128), dim3(256), 0, stream,
        readbuf, tgt, q_emb, rsum_W, rsum_b, wsum_W, wsum_b,
        succ_W, succ_b, fail_W, fail_b, diff_W, diff_b, sig, out);
}